// Round 9
// baseline (68.649 us; speedup 1.0000x reference)
//
#include <hip/hip_runtime.h>
#include <hip/hip_bf16.h>

// Problem constants
#define B_   2
#define T_   2
#define H_   56
#define W_   56
#define C_   256
#define NH_  8
#define HD_  32
#define NWW_ 14             // windows along W (W_sp=4)
#define WC_  (W_ * C_)      // 14336
#define P1_  (H_ * W_ * C_) // 802816 (one (b,t) plane)
#define VIRT_ 336.0f        // zero-logit pooled tokens folded analytically (896-560)
#define MEXP_ 16.0f         // fixed softmax max (exp2 domain)

typedef __bf16 bf16;
typedef __bf16 bf16x8 __attribute__((ext_vector_type(8)));
typedef __bf16 bf16x4 __attribute__((ext_vector_type(4)));
typedef float  f32x4  __attribute__((ext_vector_type(4)));
typedef short  s16x4  __attribute__((ext_vector_type(4)));
typedef unsigned int  uint;
typedef uint   uint4v __attribute__((ext_vector_type(4)));
typedef uint   uint2v __attribute__((ext_vector_type(2)));
typedef unsigned short u16;

__device__ __forceinline__ uint pack2(float a, float b) {
    u16 ha = __builtin_bit_cast(u16, (bf16)a);
    u16 hb = __builtin_bit_cast(u16, (bf16)b);
    return (uint)ha | ((uint)hb << 16);
}

__device__ __forceinline__ s16x4 pack4(float a, float b, float c, float d) {
    const uint2v u = {pack2(a, b), pack2(c, d)};
    return __builtin_bit_cast(s16x4, u);
}

// gather 4 bf16 at stride s (elements) -> s16x4 (V A-fragment k-slots)
__device__ __forceinline__ s16x4 g4(const bf16* __restrict__ p, int s) {
    s16x4 v;
    v[0] = __builtin_bit_cast(short, p[0]);
    v[1] = __builtin_bit_cast(short, p[s]);
    v[2] = __builtin_bit_cast(short, p[2 * s]);
    v[3] = __builtin_bit_cast(short, p[3 * s]);
    return v;
}

// ---------------------------------------------------------------------------
// Pre-kernel, 1024 threads.
// Blocks 0..55: pool (b,t,j) -> FINAL pm_k/pm_v in bf16 (quarters LDS-reduced).
// Blocks 56..447: LePE 3x3 depthwise within 56x4 strips + K/V f32->bf16 planes.
// ---------------------------------------------------------------------------
__launch_bounds__(1024, 1)
__global__ void pre_kernel(const float* __restrict__ k_in, const float* __restrict__ v_in,
                           const float* __restrict__ pool_w, const float* __restrict__ pool_b,
                           const float* __restrict__ gw, const float* __restrict__ gb,
                           bf16* __restrict__ pm_k, bf16* __restrict__ pm_v,
                           bf16* __restrict__ lepe, bf16* __restrict__ kbf,
                           bf16* __restrict__ vbf) {
    const int bid = blockIdx.x;
    const int tid = threadIdx.x;

    if (bid < 56) {
        // ---- pool: (b,t,j); threads = (quarter 0..3, c 0..255) ----
        __shared__ float pws[4][224];
        __shared__ float red[3][4][2][256];
        const int j = bid % NWW_;
        const int t = (bid / NWW_) % T_;
        const int b = bid / (NWW_ * T_);
        const int quarter = tid >> 8;
        const int c = tid & 255;

        if (tid < 896) pws[tid / 224][tid % 224] = pool_w[tid];
        __syncthreads();

        float ak[4] = {0.f, 0.f, 0.f, 0.f};
        float av[4] = {0.f, 0.f, 0.f, 0.f};
        const int n0 = quarter * 56;
        #pragma unroll 4
        for (int i = 0; i < 56; ++i) {
            const int n = n0 + i;
            const int h = n >> 2, wi = n & 3;
            const size_t off = (size_t)(b * T_ + t) * P1_ + h * WC_ + (j * 4 + wi) * C_ + c;
            const float kv = k_in[off];
            const float vv = v_in[off];
            #pragma unroll
            for (int s = 0; s < 4; ++s) {
                ak[s] += kv * pws[s][n];
                av[s] += vv * pws[s][n];
            }
        }
        if (quarter > 0) {
            #pragma unroll
            for (int s = 0; s < 4; ++s) {
                red[quarter - 1][s][0][c] = ak[s];
                red[quarter - 1][s][1][c] = av[s];
            }
        }
        __syncthreads();
        if (quarter == 0) {
            #pragma unroll
            for (int s = 0; s < 4; ++s) {
                const float bias = pool_b[s];
                const float sk = ak[s] + red[0][s][0][c] + red[1][s][0][c] + red[2][s][0][c] + bias;
                const float sv = av[s] + red[0][s][1][c] + red[1][s][1][c] + red[2][s][1][c] + bias;
                const size_t o = ((size_t)(((b * T_ + t) * 4 + s) * NWW_ + j)) * C_ + c;
                pm_k[o] = (bf16)sk;
                pm_v[o] = (bf16)sv;
            }
        }
    } else {
        // ---- LePE + K/V bf16 cvt: (bt, hq, strip-pair); threads = (hsub, c) ----
        const int r  = bid - 56;
        const int sp = r % 7;
        const int hq = (r / 7) % NWW_;
        const int bt = r / (7 * NWW_);
        const int h  = hq * 4 + (tid >> 8);
        const int c  = tid & 255;

        float wv9[9];
        #pragma unroll
        for (int k = 0; k < 9; ++k) wv9[k] = gw[c * 9 + k];
        const float bias = gb[c];

        #pragma unroll
        for (int s2 = 0; s2 < 2; ++s2) {
            const int strip = sp * 2 + s2;
            float tile[3][4];
            #pragma unroll
            for (int dy = 0; dy < 3; ++dy) {
                const int hh = h - 1 + dy;
                const bool ok = (hh >= 0 && hh < H_);
                #pragma unroll
                for (int x = 0; x < 4; ++x) {
                    tile[dy][x] = ok
                        ? v_in[(size_t)bt * P1_ + hh * WC_ + (strip * 4 + x) * C_ + c]
                        : 0.f;
                }
            }
            #pragma unroll
            for (int wi = 0; wi < 4; ++wi) {
                float acc = bias;
                #pragma unroll
                for (int dy = 0; dy < 3; ++dy) {
                    #pragma unroll
                    for (int dx = -1; dx <= 1; ++dx) {
                        const int xx = wi + dx;
                        if (xx >= 0 && xx < 4)
                            acc += wv9[dy * 3 + dx + 1] * tile[dy][xx];
                    }
                }
                const size_t oo = (size_t)bt * P1_ + h * WC_ + (strip * 4 + wi) * C_ + c;
                lepe[oo] = (bf16)acc;
                vbf[oo]  = (bf16)tile[1][wi];
                kbf[oo]  = (bf16)k_in[oo];
            }
        }
    }
}

// ---------------------------------------------------------------------------
// Streaming attention: NO LDS, NO barriers, bf16 operands straight from L2.
// 6272 independent waves; each owns ONE 16-row q-tile of one (window, head).
// Fixed-max softmax (exp2 domain), lane-local PV (16x16x16 B-operand trick),
// 336 virtual zero-logit tokens in the denominator. grid = 1568 x 256.
// ---------------------------------------------------------------------------
__launch_bounds__(256, 6)
__global__ void attn_kernel(const float* __restrict__ q_in, const bf16* __restrict__ kbf,
                            const bf16* __restrict__ vbf, const bf16* __restrict__ pm_k,
                            const bf16* __restrict__ pm_v, const bf16* __restrict__ lepe,
                            float* __restrict__ out) {
    const int tid  = threadIdx.x;
    const int lane = tid & 63;
    const int wvid = (blockIdx.x << 2) + (tid >> 6);   // 0..6271
    const int qt   = wvid % 28;                        // q-tile (16 rows)
    const int hw   = wvid / 28;                        // (window, head) 0..223
    const int nh   = hw & 7;
    const int nwi  = hw >> 3;
    const int b    = nwi / NWW_;
    const int ww   = nwi % NWW_;
    const int l15  = lane & 15;
    const int g    = lane >> 4;
    const int cbase = nh * 32;
    const float QS = 0.17677669529663687f * 1.4426950408889634f; // HD^-0.5 * log2(e)

    // ---- Q fragment (tile qt), scaled into exp2 domain ----
    bf16x8 qf;
    {
        const int qrow = qt * 16 + l15;
        const int t = qrow / 224, r = qrow % 224;
        const int h = r >> 2, wi = r & 3;
        const size_t off = (size_t)(b * T_ + t) * P1_ + h * WC_ + (ww * 4 + wi) * C_ + cbase + g * 8;
        const f32x4 a0 = *(const f32x4*)(q_in + off);
        const f32x4 a1 = *(const f32x4*)(q_in + off + 4);
        const uint4v qp = {pack2(a0[0] * QS, a0[1] * QS), pack2(a0[2] * QS, a0[3] * QS),
                           pack2(a1[0] * QS, a1[1] * QS), pack2(a1[2] * QS, a1[3] * QS)};
        qf = __builtin_bit_cast(bf16x8, qp);
    }

    f32x4 o0 = {0.f, 0.f, 0.f, 0.f}, o1 = {0.f, 0.f, 0.f, 0.f};
    float ssum = 0.f;
    const f32x4 zf = {0.f, 0.f, 0.f, 0.f};

    auto computeFull = [&](const bf16x8& KA, const bf16x8& KB, const s16x4& V00,
                           const s16x4& V01, const s16x4& V10, const s16x4& V11) {
        const f32x4 s0 = __builtin_amdgcn_mfma_f32_16x16x32_bf16(KA, qf, zf, 0, 0, 0);
        const f32x4 s1 = __builtin_amdgcn_mfma_f32_16x16x32_bf16(KB, qf, zf, 0, 0, 0);
        const float p0 = __builtin_amdgcn_exp2f(s0[0] - MEXP_);
        const float p1 = __builtin_amdgcn_exp2f(s0[1] - MEXP_);
        const float p2 = __builtin_amdgcn_exp2f(s0[2] - MEXP_);
        const float p3 = __builtin_amdgcn_exp2f(s0[3] - MEXP_);
        const float p4 = __builtin_amdgcn_exp2f(s1[0] - MEXP_);
        const float p5 = __builtin_amdgcn_exp2f(s1[1] - MEXP_);
        const float p6 = __builtin_amdgcn_exp2f(s1[2] - MEXP_);
        const float p7 = __builtin_amdgcn_exp2f(s1[3] - MEXP_);
        ssum += ((p0 + p1) + (p2 + p3)) + ((p4 + p5) + (p6 + p7));
        const s16x4 pb0 = pack4(p0, p1, p2, p3);
        const s16x4 pb1 = pack4(p4, p5, p6, p7);
        o0 = __builtin_amdgcn_mfma_f32_16x16x16bf16_1k(V00, pb0, o0, 0, 0, 0);
        o0 = __builtin_amdgcn_mfma_f32_16x16x16bf16_1k(V01, pb1, o0, 0, 0, 0);
        o1 = __builtin_amdgcn_mfma_f32_16x16x16bf16_1k(V10, pb0, o1, 0, 0, 0);
        o1 = __builtin_amdgcn_mfma_f32_16x16x16bf16_1k(V11, pb1, o1, 0, 0, 0);
    };
    auto computeHalf = [&](const bf16x8& KA, const s16x4& V00, const s16x4& V10) {
        const f32x4 s0 = __builtin_amdgcn_mfma_f32_16x16x32_bf16(KA, qf, zf, 0, 0, 0);
        const float p0 = __builtin_amdgcn_exp2f(s0[0] - MEXP_);
        const float p1 = __builtin_amdgcn_exp2f(s0[1] - MEXP_);
        const float p2 = __builtin_amdgcn_exp2f(s0[2] - MEXP_);
        const float p3 = __builtin_amdgcn_exp2f(s0[3] - MEXP_);
        ssum += (p0 + p1) + (p2 + p3);
        const s16x4 pb0 = pack4(p0, p1, p2, p3);
        o0 = __builtin_amdgcn_mfma_f32_16x16x16bf16_1k(V00, pb0, o0, 0, 0, 0);
        o1 = __builtin_amdgcn_mfma_f32_16x16x16bf16_1k(V10, pb0, o1, 0, 0, 0);
    };

    // lane-invariant element offsets
    const int koff = (l15 >> 2) * WC_ + (l15 & 3) * C_ + cbase + g * 8; // K A-frag
    const int voff = g * WC_ + cbase + l15;                            // V A-frag base

    // ---- window chunks: 2 t-planes x 7 chunks of 32 tokens ----
    for (int t = 0; t < 2; ++t) {
        const bf16* kb_ = kbf + (size_t)(b * T_ + t) * P1_ + ww * 4 * C_;
        const bf16* vb_ = vbf + (size_t)(b * T_ + t) * P1_ + ww * 4 * C_;
        for (int rc = 0; rc < 7; ++rc) {
            const int cb = rc * 8 * WC_;
            const bf16x8 ka  = *(const bf16x8*)(kb_ + cb + koff);
            const bf16x8 kb2 = *(const bf16x8*)(kb_ + cb + koff + 4 * WC_);
            const bf16* vp = vb_ + cb + voff;
            const s16x4 v00 = g4(vp, C_);
            const s16x4 v01 = g4(vp + 4 * WC_, C_);
            const s16x4 v10 = g4(vp + 16, C_);
            const s16x4 v11 = g4(vp + 4 * WC_ + 16, C_);
            computeFull(ka, kb2, v00, v01, v10, v11);
        }
    }

    // ---- pooled chunks: 112 real tokens; chunk 3 is a half ----
    #pragma unroll
    for (int pc = 0; pc < 4; ++pc) {
        const int i0 = pc * 32 + l15;
        const int t0 = i0 / 56, r0 = i0 - 56 * t0;
        const bf16x8 ka = *(const bf16x8*)(pm_k + (size_t)((b * T_ + t0) * 56 + r0) * C_
                                                + cbase + g * 8);
        float f0[4], fh0[4];
        #pragma unroll
        for (int e = 0; e < 4; ++e) {
            const int iv = pc * 32 + g * 4 + e;
            const int tv = iv / 56, rv = iv - 56 * tv;
            const bf16* pv = pm_v + (size_t)((b * T_ + tv) * 56 + rv) * C_ + cbase + l15;
            f0[e] = (float)pv[0]; fh0[e] = (float)pv[16];
        }
        const s16x4 v00 = pack4(f0[0], f0[1], f0[2], f0[3]);
        const s16x4 v10 = pack4(fh0[0], fh0[1], fh0[2], fh0[3]);

        if (pc < 3) {
            const int i1 = i0 + 16;
            const int t1 = i1 / 56, r1 = i1 - 56 * t1;
            const bf16x8 kb2 = *(const bf16x8*)(pm_k + (size_t)((b * T_ + t1) * 56 + r1) * C_
                                                     + cbase + g * 8);
            float f1[4], fh1[4];
            #pragma unroll
            for (int e = 0; e < 4; ++e) {
                const int iv = pc * 32 + 16 + g * 4 + e;
                const int tv = iv / 56, rv = iv - 56 * tv;
                const bf16* pv = pm_v + (size_t)((b * T_ + tv) * 56 + rv) * C_ + cbase + l15;
                f1[e] = (float)pv[0]; fh1[e] = (float)pv[16];
            }
            const s16x4 v01 = pack4(f1[0], f1[1], f1[2], f1[3]);
            const s16x4 v11 = pack4(fh1[0], fh1[1], fh1[2], fh1[3]);
            computeFull(ka, kb2, v00, v01, v10, v11);
        } else {
            computeHalf(ka, v00, v10);
        }
    }

    // ---- epilogue: denominator reduce, virtual zeros, LePE, store ----
    float den = ssum;
    den += __shfl_xor(den, 16);
    den += __shfl_xor(den, 32);
    den += VIRT_ * 0.0000152587890625f; // 336 * 2^-16
    const float osc = 1.0f / den;       // valid in every lane, for q = l15

    // o{0,1} reg r = O[q=l15][cbase + h2*16 + g*4 + r] — fully lane-local
    const int qrow = qt * 16 + l15;
    const int t = qrow / 224, rr = qrow % 224;
    const int h = rr >> 2, wi = rr & 3;
    const size_t off = (size_t)(b * T_ + t) * P1_ + h * WC_ + (ww * 4 + wi) * C_ + cbase;
    {
        const int co = g * 4;
        const bf16x4 lp0 = *(const bf16x4*)(lepe + off + co);
        const bf16x4 lp1 = *(const bf16x4*)(lepe + off + 16 + co);
        f32x4 val0, val1;
        #pragma unroll
        for (int r = 0; r < 4; ++r) {
            val0[r] = o0[r] * osc + (float)lp0[r];
            val1[r] = o1[r] * osc + (float)lp1[r];
        }
        *(f32x4*)(out + off + co)      = val0;
        *(f32x4*)(out + off + 16 + co) = val1;
    }
}

// ---------------------------------------------------------------------------
extern "C" void kernel_launch(void* const* d_in, const int* in_sizes, int n_in,
                              void* d_out, int out_size, void* d_ws, size_t ws_size,
                              hipStream_t stream) {
    const float* qkv = (const float*)d_in[0];
    const float* gw  = (const float*)d_in[1];
    const float* gb  = (const float*)d_in[2];
    const float* pw  = (const float*)d_in[3];
    const float* pb  = (const float*)d_in[4];

    const size_t plane = (size_t)B_ * T_ * H_ * W_ * C_; // 3,211,264
    const float* q_in = qkv;
    const float* k_in = qkv + plane;
    const float* v_in = qkv + 2 * plane;

    const size_t pm_elems = (size_t)B_ * T_ * 4 * NWW_ * C_; // 57,344
    bf16* pm_k = (bf16*)d_ws;
    bf16* pm_v = pm_k + pm_elems;
    bf16* lepe = pm_v + pm_elems;
    bf16* kbf  = lepe + plane;
    bf16* vbf  = kbf + plane;
    float* outp = (float*)d_out;

    hipLaunchKernelGGL(pre_kernel, dim3(56 + 392), dim3(1024), 0, stream,
                       k_in, v_in, pw, pb, gw, gb, pm_k, pm_v, lepe, kbf, vbf);
    hipLaunchKernelGGL(attn_kernel, dim3(1568), dim3(256), 0, stream,
                       q_in, kbf, vbf, pm_k, pm_v, lepe, outp);
}

// Round 10
// 52.586 us; speedup vs baseline: 1.3055x; 1.3055x over previous
//
#include <hip/hip_runtime.h>
#include <hip/hip_bf16.h>

// Problem constants
#define B_    2
#define T_    2
#define H_    56
#define W_    56
#define C_    256
#define NWW_  14             // windows along W (W_sp=4)
#define WC_   (W_ * C_)      // 14336
#define P1_   (H_ * W_ * C_) // 802816 (one (b,t) plane)
#define NWIN_ 448            // tokens per window
#define NPOOL_ 128           // pooled slots (112 real + 16 zero)
#define VIRT_ 320.0f         // zero-logit tokens folded analytically (896-576)
#define MEXP_ 16.0f          // fixed softmax max (exp2 domain)

typedef __bf16 bf16;
typedef __bf16 bf16x8 __attribute__((ext_vector_type(8)));
typedef __bf16 bf16x4 __attribute__((ext_vector_type(4)));
typedef float  f32x4  __attribute__((ext_vector_type(4)));
typedef short  s16x4  __attribute__((ext_vector_type(4)));
typedef short  s16x8  __attribute__((ext_vector_type(8)));
typedef unsigned int  uint;
typedef uint   uint4v __attribute__((ext_vector_type(4)));
typedef uint   uint2v __attribute__((ext_vector_type(2)));
typedef unsigned short u16;

__device__ __forceinline__ uint pack2(float a, float b) {
    u16 ha = __builtin_bit_cast(u16, (bf16)a);
    u16 hb = __builtin_bit_cast(u16, (bf16)b);
    return (uint)ha | ((uint)hb << 16);
}
__device__ __forceinline__ s16x4 pack4(float a, float b, float c, float d) {
    const uint2v u = {pack2(a, b), pack2(c, d)};
    return __builtin_bit_cast(s16x4, u);
}

// ---------------------------------------------------------------------------
// Pre-kernel, 1024 threads.
// Blocks 0..55  : pool (b,t,j) -> kp/vp bf16 slots (+ zero-pad slots 112..127).
// Blocks 56..447: one 32-token chunk of one window: LePE + K relayout + V
//                 transpose (LDS bounce) into MFMA-native layouts.
// ---------------------------------------------------------------------------
__launch_bounds__(1024, 1)
__global__ void pre_kernel(const float* __restrict__ k_in, const float* __restrict__ v_in,
                           const float* __restrict__ pool_w, const float* __restrict__ pool_b,
                           const float* __restrict__ gw, const float* __restrict__ gb,
                           bf16* __restrict__ kw, bf16* __restrict__ vw,
                           bf16* __restrict__ lepew, bf16* __restrict__ kp,
                           bf16* __restrict__ vp) {
    __shared__ float pws[4][224];
    __shared__ float red[3][4][2][256];
    __shared__ u16  tileT[256 * 33];   // [c][tok] V transpose bounce

    const int bid = blockIdx.x;
    const int tid = threadIdx.x;

    if (bid < 56) {
        // ---- pool: (b,t,j); threads = (quarter 0..3, c 0..255) ----
        const int j = bid % NWW_;
        const int t = (bid / NWW_) % T_;
        const int b = bid / (NWW_ * T_);
        const int quarter = tid >> 8;
        const int c = tid & 255;
        const int nh = c >> 5, hd = c & 31;
        const int bn = b * 8 + nh;

        if (tid < 896) pws[tid / 224][tid % 224] = pool_w[tid];
        __syncthreads();

        float ak[4] = {0.f, 0.f, 0.f, 0.f};
        float av[4] = {0.f, 0.f, 0.f, 0.f};
        const int n0 = quarter * 56;
        #pragma unroll 4
        for (int i = 0; i < 56; ++i) {
            const int n = n0 + i;
            const int h = n >> 2, wi = n & 3;
            const size_t off = (size_t)(b * T_ + t) * P1_ + h * WC_ + (j * 4 + wi) * C_ + c;
            const float kv = k_in[off];
            const float vv = v_in[off];
            #pragma unroll
            for (int s = 0; s < 4; ++s) {
                ak[s] += kv * pws[s][n];
                av[s] += vv * pws[s][n];
            }
        }
        if (quarter > 0) {
            #pragma unroll
            for (int s = 0; s < 4; ++s) {
                red[quarter - 1][s][0][c] = ak[s];
                red[quarter - 1][s][1][c] = av[s];
            }
        }
        __syncthreads();
        if (quarter == 0) {
            #pragma unroll
            for (int s = 0; s < 4; ++s) {
                const float bias = pool_b[s];
                const float sk = ak[s] + red[0][s][0][c] + red[1][s][0][c] + red[2][s][0][c] + bias;
                const float sv = av[s] + red[0][s][1][c] + red[1][s][1][c] + red[2][s][1][c] + bias;
                const int n = t * 56 + s * 14 + j;             // pooled token index
                kp[((size_t)bn * NPOOL_ + n) * 32 + hd] = (bf16)sk;
                const int i5 = n & 31;
                const int slot = ((i5 & 15) >> 2) * 8 + (i5 >> 4) * 4 + (i5 & 3);
                vp[(((size_t)bn * 4 + (n >> 5)) * 32 + hd) * 32 + slot] = (bf16)sv;
            }
        }
        // ---- zero-pad slots (tokens 112..127) — done by (t==0, j==0) blocks ----
        if (t == 0 && j == 0) {
            for (int z = tid; z < 2048; z += 1024) {           // kp zeros
                const int nh2 = z >> 8, off = z & 255;
                ((uint*)kp)[((size_t)(b * 8 + nh2) * NPOOL_ + 112) * 16 + off] = 0u;
            }
            {                                                  // vp zeros (hi=1 slots, chunk 3)
                const int z = tid;
                const int nh2 = z >> 7, hd2 = (z >> 2) & 31, gg = z & 3;
                const size_t base16 = (((size_t)(b * 8 + nh2) * 4 + 3) * 32 + hd2) * 32 + gg * 8 + 4;
                ((uint*)vp)[base16 / 2]     = 0u;
                ((uint*)vp)[base16 / 2 + 1] = 0u;
            }
        }
    } else {
        // ---- chunk block: (b, t, ww, rc); threads = (hs 0..3, c 0..255) ----
        const int r  = bid - 56;
        const int rc = r % 7;
        const int ww = (r / 7) % NWW_;
        const int t  = (r / 98) % T_;
        const int b  = r / 196;
        const int hs = tid >> 8;
        const int c  = tid & 255;
        const int nh = c >> 5, hd = c & 31;
        const size_t bt = (size_t)(b * T_ + t) * P1_;
        const size_t winbase = ((size_t)((b * 8 + nh) * NWW_ + ww)) * NWIN_ * 32;

        float wv9[9];
        #pragma unroll
        for (int k = 0; k < 9; ++k) wv9[k] = gw[c * 9 + k];
        const float bias = gb[c];

        // v rows rc*8+hs*2-1 .. +2
        float tile[4][4];
        #pragma unroll
        for (int dy = 0; dy < 4; ++dy) {
            const int hh = rc * 8 + hs * 2 - 1 + dy;
            const bool ok = (hh >= 0 && hh < H_);
            #pragma unroll
            for (int x = 0; x < 4; ++x)
                tile[dy][x] = ok ? v_in[bt + hh * WC_ + (ww * 4 + x) * C_ + c] : 0.f;
        }

        #pragma unroll
        for (int e = 0; e < 2; ++e) {
            const int h = rc * 8 + hs * 2 + e;
            #pragma unroll
            for (int wi = 0; wi < 4; ++wi) {
                const int tokc = hs * 8 + e * 4 + wi;          // 0..31 in chunk
                const int tokw = t * 224 + h * 4 + wi;         // token in window
                // LePE conv
                float acc = bias;
                #pragma unroll
                for (int dy = 0; dy < 3; ++dy) {
                    #pragma unroll
                    for (int dx = -1; dx <= 1; ++dx) {
                        const int xx = wi + dx;
                        if (xx >= 0 && xx < 4)
                            acc += wv9[dy * 3 + dx + 1] * tile[e + dy][xx];
                    }
                }
                lepew[winbase + (size_t)tokw * 32 + hd] = (bf16)acc;
                // K relayout
                kw[winbase + (size_t)tokw * 32 + hd] =
                    (bf16)k_in[bt + h * WC_ + (ww * 4 + wi) * C_ + c];
                // V into LDS transpose tile
                tileT[c * 33 + tokc] = __builtin_bit_cast(u16, (bf16)tile[1 + e][wi]);
            }
        }
        __syncthreads();

        // vw writeout: chunk ch = t*7+rc ; [b,nh,ww][ch][hd][slot]
        const int ch = t * 7 + rc;
        #pragma unroll
        for (int rep = 0; rep < 4; ++rep) {
            const int u  = tid + rep * 1024;      // 0..4095 uints
            const int cc = u >> 4;
            const int p  = u & 15;
            const int tok0 = ((p >> 1) & 1) * 16 + (p >> 2) * 4 + ((2 * p) & 3);
            const uint val = (uint)tileT[cc * 33 + tok0] |
                             ((uint)tileT[cc * 33 + tok0 + 1] << 16);
            const size_t dst = (((size_t)((b * 8 + (cc >> 5)) * NWW_ + ww)) * 14 + ch) * 1024
                             + (cc & 31) * 32;
            ((uint*)vw)[dst / 2 + p] = val;
        }
    }
}

// ---------------------------------------------------------------------------
// Streaming attention with MFMA-native operand layouts: every inner-loop load
// is a wave-contiguous b128 (4 VMEM per 32-token chunk). No LDS, no barriers.
// 6272 waves; each owns ONE 16-row q-tile. Fixed-max softmax (exp2 domain),
// lane-local PV, 320 virtual zero-logit tokens. grid = 1568 x 256.
// ---------------------------------------------------------------------------
__launch_bounds__(256, 6)
__global__ void attn_kernel(const float* __restrict__ q_in, const bf16* __restrict__ kw,
                            const bf16* __restrict__ vw, const bf16* __restrict__ lepew,
                            const bf16* __restrict__ kp, const bf16* __restrict__ vp,
                            float* __restrict__ out) {
    const int tid  = threadIdx.x;
    const int lane = tid & 63;
    const int wvid = (blockIdx.x << 2) + (tid >> 6);   // 0..6271
    const int qt   = wvid % 28;
    const int hw   = wvid / 28;                        // 0..223
    const int nh   = hw & 7;
    const int nwi  = hw >> 3;
    const int b    = nwi / NWW_;
    const int ww   = nwi % NWW_;
    const int l15  = lane & 15;
    const int g    = lane >> 4;
    const int bn   = b * 8 + nh;
    const int cbase = nh * 32;
    const float QS = 0.17677669529663687f * 1.4426950408889634f; // HD^-0.5 * log2(e)

    // ---- Q fragment (f32 image layout, once per wave) ----
    bf16x8 qf;
    {
        const int qrow = qt * 16 + l15;
        const int t = qrow / 224, r = qrow % 224;
        const int h = r >> 2, wi = r & 3;
        const size_t off = (size_t)(b * T_ + t) * P1_ + h * WC_ + (ww * 4 + wi) * C_ + cbase + g * 8;
        const f32x4 a0 = *(const f32x4*)(q_in + off);
        const f32x4 a1 = *(const f32x4*)(q_in + off + 4);
        const uint4v qp = {pack2(a0[0] * QS, a0[1] * QS), pack2(a0[2] * QS, a0[3] * QS),
                           pack2(a1[0] * QS, a1[1] * QS), pack2(a1[2] * QS, a1[3] * QS)};
        qf = __builtin_bit_cast(bf16x8, qp);
    }

    f32x4 o0 = {0.f, 0.f, 0.f, 0.f}, o1 = {0.f, 0.f, 0.f, 0.f};
    float ssum = 0.f;
    const f32x4 zf = {0.f, 0.f, 0.f, 0.f};

    auto computeFull = [&](const bf16x8& KA, const bf16x8& KB,
                           const bf16x8& VA, const bf16x8& VB) {
        const f32x4 s0 = __builtin_amdgcn_mfma_f32_16x16x32_bf16(KA, qf, zf, 0, 0, 0);
        const f32x4 s1 = __builtin_amdgcn_mfma_f32_16x16x32_bf16(KB, qf, zf, 0, 0, 0);
        const float p0 = __builtin_amdgcn_exp2f(s0[0] - MEXP_);
        const float p1 = __builtin_amdgcn_exp2f(s0[1] - MEXP_);
        const float p2 = __builtin_amdgcn_exp2f(s0[2] - MEXP_);
        const float p3 = __builtin_amdgcn_exp2f(s0[3] - MEXP_);
        const float p4 = __builtin_amdgcn_exp2f(s1[0] - MEXP_);
        const float p5 = __builtin_amdgcn_exp2f(s1[1] - MEXP_);
        const float p6 = __builtin_amdgcn_exp2f(s1[2] - MEXP_);
        const float p7 = __builtin_amdgcn_exp2f(s1[3] - MEXP_);
        ssum += ((p0 + p1) + (p2 + p3)) + ((p4 + p5) + (p6 + p7));
        const s16x4 pb0 = pack4(p0, p1, p2, p3);
        const s16x4 pb1 = pack4(p4, p5, p6, p7);
        const s16x8 va = __builtin_bit_cast(s16x8, VA);
        const s16x8 vb = __builtin_bit_cast(s16x8, VB);
        const s16x4 v00 = {va[0], va[1], va[2], va[3]};
        const s16x4 v01 = {va[4], va[5], va[6], va[7]};
        const s16x4 v10 = {vb[0], vb[1], vb[2], vb[3]};
        const s16x4 v11 = {vb[4], vb[5], vb[6], vb[7]};
        o0 = __builtin_amdgcn_mfma_f32_16x16x16bf16_1k(v00, pb0, o0, 0, 0, 0);
        o0 = __builtin_amdgcn_mfma_f32_16x16x16bf16_1k(v01, pb1, o0, 0, 0, 0);
        o1 = __builtin_amdgcn_mfma_f32_16x16x16bf16_1k(v10, pb0, o1, 0, 0, 0);
        o1 = __builtin_amdgcn_mfma_f32_16x16x16bf16_1k(v11, pb1, o1, 0, 0, 0);
    };

    // ---- 14 window chunks: all loads wave-contiguous b128 ----
    const bf16* kwb = kw + ((size_t)(bn * NWW_ + ww)) * NWIN_ * 32;
    const bf16* vwb = vw + ((size_t)(bn * NWW_ + ww)) * 14 * 1024;
    const int ko = l15 * 32 + g * 8;
    const int ko2 = (16 + l15) * 32 + g * 8;
    #pragma unroll 2
    for (int ch = 0; ch < 14; ++ch) {
        const bf16x8 ka = *(const bf16x8*)(kwb + ch * 1024 + ko);
        const bf16x8 kb = *(const bf16x8*)(kwb + ch * 1024 + ko2);
        const bf16x8 vA = *(const bf16x8*)(vwb + ch * 1024 + ko);
        const bf16x8 vB = *(const bf16x8*)(vwb + ch * 1024 + ko2);
        computeFull(ka, kb, vA, vB);
    }

    // ---- 4 pooled chunks (112 real + 16 zero tokens) ----
    const bf16* kpb = kp + (size_t)bn * NPOOL_ * 32;
    const bf16* vpb = vp + (size_t)bn * 4 * 1024;
    #pragma unroll 2
    for (int pc = 0; pc < 4; ++pc) {
        const bf16x8 ka = *(const bf16x8*)(kpb + pc * 1024 + ko);
        const bf16x8 kb = *(const bf16x8*)(kpb + pc * 1024 + ko2);
        const bf16x8 vA = *(const bf16x8*)(vpb + pc * 1024 + ko);
        const bf16x8 vB = *(const bf16x8*)(vpb + pc * 1024 + ko2);
        computeFull(ka, kb, vA, vB);
    }

    // ---- epilogue ----
    float den = ssum;
    den += __shfl_xor(den, 16);
    den += __shfl_xor(den, 32);
    den += VIRT_ * 0.0000152587890625f; // 320 * 2^-16
    const float osc = 1.0f / den;       // for q = l15, valid in every lane

    const int qrow = qt * 16 + l15;
    const bf16* lw = lepew + ((size_t)(bn * NWW_ + ww)) * NWIN_ * 32 + (size_t)qrow * 32;
    const bf16x4 lp0 = *(const bf16x4*)(lw + g * 4);
    const bf16x4 lp1 = *(const bf16x4*)(lw + 16 + g * 4);

    const int t = qrow / 224, rr = qrow % 224;
    const int h = rr >> 2, wi = rr & 3;
    const size_t off = (size_t)(b * T_ + t) * P1_ + h * WC_ + (ww * 4 + wi) * C_ + cbase;
    f32x4 val0, val1;
    #pragma unroll
    for (int r = 0; r < 4; ++r) {
        val0[r] = o0[r] * osc + (float)lp0[r];
        val1[r] = o1[r] * osc + (float)lp1[r];
    }
    *(f32x4*)(out + off + g * 4)      = val0;
    *(f32x4*)(out + off + 16 + g * 4) = val1;
}

// ---------------------------------------------------------------------------
extern "C" void kernel_launch(void* const* d_in, const int* in_sizes, int n_in,
                              void* d_out, int out_size, void* d_ws, size_t ws_size,
                              hipStream_t stream) {
    const float* qkv = (const float*)d_in[0];
    const float* gw  = (const float*)d_in[1];
    const float* gb  = (const float*)d_in[2];
    const float* pw  = (const float*)d_in[3];
    const float* pb  = (const float*)d_in[4];

    const size_t plane = (size_t)B_ * T_ * H_ * W_ * C_; // 3,211,264
    const float* q_in = qkv;
    const float* k_in = qkv + plane;
    const float* v_in = qkv + 2 * plane;

    bf16* kw    = (bf16*)d_ws;           // 3,211,264 elems
    bf16* vw    = kw + plane;            // 3,211,264
    bf16* lepew = vw + plane;            // 3,211,264
    bf16* kp    = lepew + plane;         // 65,536
    bf16* vp    = kp + (size_t)16 * NPOOL_ * 32; // 65,536
    float* outp = (float*)d_out;

    hipLaunchKernelGGL(pre_kernel, dim3(56 + 392), dim3(1024), 0, stream,
                       k_in, v_in, pw, pb, gw, gb, kw, vw, lepew, kp, vp);
    hipLaunchKernelGGL(attn_kernel, dim3(1568), dim3(256), 0, stream,
                       q_in, kw, vw, lepew, kp, vp, outp);
}